// Round 5
// baseline (40.462 us; speedup 1.0000x reference)
//
#include <hip/hip_runtime.h>
#include <hip/hip_bf16.h>

#define N 4096
#define FIN 128
#define U0 16
#define H0 4
#define MAXD 128   // padded neighbor-list stride; P(deg>128), Binom(4096,0.01) ~ 0

// ---------------------------------------------------------------------------
// K0: h0 = x@w0 ([4096,128]@[128,16]), a1/a2 = h0@aw, S0 += column partials.
// 256 blocks x 256 threads (16 rows x 16 units each).
// ---------------------------------------------------------------------------
__global__ void gemm0(const float* __restrict__ x, const float* __restrict__ w0,
                      const float* __restrict__ aw1, const float* __restrict__ aw2,
                      float* __restrict__ h0, float* __restrict__ a1,
                      float* __restrict__ a2, float* __restrict__ S0) {
    __shared__ float xs[16][FIN + 1];
    __shared__ float ws[FIN][U0];
    __shared__ float hs[16][U0 + 1];
    const int t = threadIdx.x;
    const int r0 = blockIdx.x * 16;

    for (int k = t; k < FIN * U0; k += 256) ws[k / U0][k % U0] = w0[k];
    for (int k = t; k < 16 * FIN; k += 256)
        xs[k / FIN][k % FIN] = x[(size_t)(r0 + k / FIN) * FIN + (k % FIN)];
    __syncthreads();

    const int r = t / U0, u = t % U0;
    float acc = 0.f;
    #pragma unroll 8
    for (int k = 0; k < FIN; ++k) acc += xs[r][k] * ws[k][u];
    hs[r][u] = acc;
    h0[(size_t)(r0 + r) * U0 + u] = acc;
    __syncthreads();

    if (t < 16 * H0) {                 // 64 threads: (row, head)
        const int rr = t / H0, hh = t % H0;
        float s1 = 0.f, s2 = 0.f;
        #pragma unroll
        for (int u2 = 0; u2 < U0; ++u2) {
            float hv = hs[rr][u2];
            s1 += hv * aw1[u2 * H0 + hh];
            s2 += hv * aw2[u2 * H0 + hh];
        }
        a1[(r0 + rr) * H0 + hh] = s1;
        a2[(r0 + rr) * H0 + hh] = s2;
    } else if (t >= 128 && t < 144) {  // 16 threads: column partial -> S0
        const int d = t - 128;
        float s = 0.f;
        #pragma unroll
        for (int rr = 0; rr < 16; ++rr) s += hs[rr][d];
        atomicAdd(&S0[d], s);          // 16 addresses x 256 writers: benign
    }
}

// ---------------------------------------------------------------------------
// K1: fused CSR-build + layer-0 attention + hp = h1@w1, one block per row.
// The row's neighbor list never leaves LDS; the attention gather tail
// overlaps other blocks' adj streaming (kernel stays memory-bound on adj).
// S1 accumulated via 256-way-spread atomics (<=16 RMWs per address).
// ---------------------------------------------------------------------------
__global__ void k1_csr_attn0(const float* __restrict__ adj,
                             const float* __restrict__ a1, const float* __restrict__ a2,
                             const float* __restrict__ h0, const float* __restrict__ S0,
                             const float* __restrict__ w1,
                             int* __restrict__ deg, int* __restrict__ cols,
                             float* __restrict__ hp, float* __restrict__ S1part) {
    const int row = blockIdx.x;
    const int t = threadIdx.x;
    const int lane = t & 63, wid = t >> 6;

    __shared__ int cls[MAXD];
    __shared__ int wsum[4];
    __shared__ int dgs;
    __shared__ float ln[4][64];
    __shared__ float ld[4][64];

    // ---- stream adj row (16 KB), count nonzeros ----
    const float4* __restrict__ arow =
        reinterpret_cast<const float4*>(adj + (size_t)row * N);
    float4 v[4];
    int c = 0;
    #pragma unroll
    for (int p = 0; p < 4; ++p) {
        v[p] = arow[t + 256 * p];
        c += (v[p].x != 0.f) + (v[p].y != 0.f) + (v[p].z != 0.f) + (v[p].w != 0.f);
    }

    // ---- inclusive wave scan (6 shfl steps) + cross-wave offsets ----
    int sc = c;
    #pragma unroll
    for (int s = 1; s < 64; s <<= 1) {
        int u = __shfl_up(sc, s);
        if (lane >= s) sc += u;
    }
    if (lane == 63) wsum[wid] = sc;
    __syncthreads();
    int base = 0;
    #pragma unroll
    for (int w2 = 0; w2 < 4; ++w2)
        if (w2 < wid) base += wsum[w2];
    const int off = base + sc - c;
    if (t == 255) {
        const int dgv = min(base + sc, MAXD);
        dgs = dgv;
        deg[row] = dgv;
    }

    // ---- compact column indices into LDS ----
    int w = off;
    #pragma unroll
    for (int p = 0; p < 4; ++p) {
        const int j0 = (t + 256 * p) * 4;
        if (v[p].x != 0.f && w < MAXD) cls[w++] = j0;
        if (v[p].y != 0.f && w < MAXD) cls[w++] = j0 + 1;
        if (v[p].z != 0.f && w < MAXD) cls[w++] = j0 + 2;
        if (v[p].w != 0.f && w < MAXD) cls[w++] = j0 + 3;
    }
    __syncthreads();
    const int dg = dgs;

    // ---- persist CSR row for the layer-1 kernel (coalesced) ----
    if (t < dg) cols[(size_t)row * MAXD + t] = cls[t];

    // ---- layer-0 attention: 4 waves stride the LDS neighbor list ----
    const int hh = lane >> 4, d = lane & 15;
    const float a1v = a1[row * H0 + hh];
    float accn = 0.f, accd = 0.f;
    for (int k = wid; k < dg; k += 4) {
        const int j = cls[k];                      // LDS, wave-uniform
        float cc = a1v + a2[j * H0 + hh];
        cc = cc > 0.f ? cc : 0.f;
        const float e = __expf(cc) - 1.f;
        accn = fmaf(e, h0[(size_t)j * U0 + d], accn);
        accd += e;
    }
    ln[wid][lane] = accn;
    ld[wid][lane] = accd;
    __syncthreads();

    if (t < 64) {
        const float an = ln[0][t] + ln[1][t] + ln[2][t] + ln[3][t];
        const float ad = ld[0][t] + ld[1][t] + ld[2][t] + ld[3][t];
        float o = (an + S0[t & 15]) / (ad + (float)N);
        o = o > 0.f ? o : 0.f;                     // relu -> h1[row, t]

        float pv = o * w1[t];                      // hp[row] = h1[row,:].w1
        #pragma unroll
        for (int offp = 32; offp; offp >>= 1) pv += __shfl_down(pv, offp);
        if (t == 0) {
            hp[row] = pv;
            atomicAdd(&S1part[row & 255], pv);     // spread: <=16 RMW/address
        }
    }
}

// ---------------------------------------------------------------------------
// K2: layer-1 sparse attention (scalar feature) + sigmoid -> out [4096].
// S1 = reduce of 256 partials (L2-hot, 1 read/thread). hp is 16 KB -> L1/L2
// resident; gather is ~1 iteration per lane. 4 rows/block, one wave per row.
// ---------------------------------------------------------------------------
__global__ void attn1(const float* __restrict__ hp, const float* __restrict__ S1part,
                      const float* __restrict__ aw11, const float* __restrict__ aw21,
                      const int* __restrict__ deg, const int* __restrict__ cols,
                      float* __restrict__ out) {
    __shared__ float s1red[4];
    const int t = threadIdx.x;
    const int w = t >> 6, lane = t & 63;

    float s = S1part[t];                           // 256 threads, 256 partials
    #pragma unroll
    for (int o = 32; o; o >>= 1) s += __shfl_down(s, o);
    if (lane == 0) s1red[w] = s;
    __syncthreads();
    const float S1 = s1red[0] + s1red[1] + s1red[2] + s1red[3];

    const int i = blockIdx.x * 4 + w;
    const float w1v = aw11[0], w2v = aw21[0];
    const float a1v = hp[i] * w1v;
    const int dg = deg[i];
    const int* __restrict__ cl = cols + (size_t)i * MAXD;

    float accn = 0.f, accd = 0.f;
    for (int k = lane; k < dg; k += 64) {
        const int j = cl[k];
        const float hj = hp[j];
        float cc = a1v + hj * w2v;
        cc = cc > 0.f ? cc : 0.f;
        const float e = __expf(cc) - 1.f;
        accn = fmaf(e, hj, accn);
        accd += e;
    }
    #pragma unroll
    for (int o = 32; o; o >>= 1) {
        accn += __shfl_down(accn, o);
        accd += __shfl_down(accd, o);
    }
    if (lane == 0) {
        const float v = (accn + S1) / (accd + (float)N);
        out[i] = 1.f / (1.f + __expf(-v));
    }
}

// ---------------------------------------------------------------------------
extern "C" void kernel_launch(void* const* d_in, const int* in_sizes, int n_in,
                              void* d_out, int out_size, void* d_ws, size_t ws_size,
                              hipStream_t stream) {
    const float* x    = (const float*)d_in[0];
    const float* adj  = (const float*)d_in[1];
    const float* w0   = (const float*)d_in[2];
    const float* aw10 = (const float*)d_in[3];
    const float* aw20 = (const float*)d_in[4];
    const float* w1   = (const float*)d_in[5];
    const float* aw11 = (const float*)d_in[6];
    const float* aw21 = (const float*)d_in[7];
    float* out = (float*)d_out;

    char* p = (char*)d_ws;
    auto alloc = [&](size_t bytes) {
        char* r = p;
        p += (bytes + 255) & ~(size_t)255;
        return r;
    };
    float* h0     = (float*)alloc((size_t)N * U0 * 4);
    float* a1     = (float*)alloc((size_t)N * H0 * 4);
    float* a2     = (float*)alloc((size_t)N * H0 * 4);
    float* S0     = (float*)alloc(256);            // 16 floats used
    float* S1part = (float*)alloc(1024);           // 256 floats
    float* hp     = (float*)alloc((size_t)N * 4);
    int*   deg    = (int*)alloc((size_t)N * 4);
    int*   cols   = (int*)alloc((size_t)N * MAXD * 4);

    hipMemsetAsync(S0, 0, 256 + 1024, stream);     // zero S0 + S1part (contiguous)
    gemm0<<<N / 16, 256, 0, stream>>>(x, w0, aw10, aw20, h0, a1, a2, S0);
    k1_csr_attn0<<<N, 256, 0, stream>>>(adj, a1, a2, h0, S0, w1,
                                        deg, cols, hp, S1part);
    attn1<<<N / 4, 256, 0, stream>>>(hp, S1part, aw11, aw21, deg, cols, out);
}